// Round 11
// baseline (363.511 us; speedup 1.0000x reference)
//
#include <hip/hip_runtime.h>

// ---------------------------------------------------------------------------
// GCN encoder, bf16 staging + MFMA GEMMs + bpermute-broadcast gather agg.
//   h  = relu(Agg(x@W1) + b1);  [mu|lv] = Agg(h@[Wmu|Wlv]) + bias
// Agg(p)[i] = dinv[i] * ( sum_{e: dst=i} p[src]*dinv[src] + p[i]*dinv[i] )
// Agg: 4 nodes/wave, 16 lanes x 8ch dwordx4 (full 256B row/instr), bpermute
// broadcast, 16-deep load batching, idle slots read zeroed row n. R1/R7
// A/B (73% vs 36% occ, both 64us, FETCH 189MB) => random-256B-line wall;
// agg body frozen. R8: agg_relu fused with GEMM2 (one WG's 16 rows = one
// MFMA A-tile, 74us, kept). R10: 2-kernel zero-coordination build (kept).
// R11: bucket_build OVERLAPPED with gemm1 in one dispatch (blockIdx split).
// To break the only cross-dependency, p1 is UNFOLDED (gemm1 writes bf16(acc),
// no dinv); agg_gemm2's gather applies dinv[src] per edge via a second
// bpermute batch + FMA (R0 structure, measured at the same agg wall).
// p2 stays folded, agg_out unchanged. 4 launches.
// Requires n <= 131072 (n = 100000 here).
// ---------------------------------------------------------------------------

#define C_IN  256
#define HID   128
#define C_OUT 64
#define NBUCK 1024
#define NSEG  256
#define CAPB  4096
#define EBCAP 4608

typedef __attribute__((ext_vector_type(8))) short bf16x8;
typedef __attribute__((ext_vector_type(4))) float f32x4;

__device__ inline unsigned short f2bf(float f) {  // round-to-nearest-even
  unsigned u = __float_as_uint(f);
  unsigned r = u + 0x7FFF + ((u >> 16) & 1);
  return (unsigned short)(r >> 16);
}
__device__ inline float bflo(unsigned v) { return __uint_as_float(v << 16); }
__device__ inline float bfhi(unsigned v) { return __uint_as_float(v & 0xFFFF0000u); }

// ---------------- P1: per-segment bin (count+scan+scatter, private region) ---
// WGs [0,NSEG): segment binning. WGs [NSEG,NSEG+7): weight prep + zero rows.
__global__ __launch_bounds__(1024) void k_seg_bin(
    const int* __restrict__ src, const int* __restrict__ dst, int E, int cap,
    int* __restrict__ cnt_arr, int* __restrict__ off_arr,
    unsigned* __restrict__ binned,
    const float* __restrict__ W1, const float* __restrict__ Wmu,
    const float* __restrict__ Wlv,
    unsigned short* __restrict__ bswz1, unsigned short* __restrict__ bswz2,
    unsigned* __restrict__ p1z, unsigned* __restrict__ p2z) {
  int tid = threadIdx.x;
  int wg = blockIdx.x;
  if (wg >= NSEG) {
    // ---- prep branch: Bswz[s][t][L][j] = bf16(B[s*32+(L>>4)*8+j][t*16+(L&15)])
    int idx = (wg - NSEG) * 1024 + tid;
    if (idx < 4096) {            // W1: (256/32)*8*64
      int L = idx & 63, t = (idx >> 6) & 7, s = idx >> 9;
      const float* srcp = W1 + (size_t)(s * 32 + ((L >> 4) << 3)) * 128 + t * 16 + (L & 15);
      unsigned short* dstp = bswz1 + (size_t)idx * 8;
#pragma unroll
      for (int j = 0; j < 8; j++) dstp[j] = f2bf(srcp[(size_t)j * 128]);
    } else if (idx < 6144) {     // [Wmu|Wlv]: (128/32)*8*64
      int id2 = idx - 4096;
      int L = id2 & 63, t = (id2 >> 6) & 7, s = id2 >> 9;
      int nn = t * 16 + (L & 15);
      int k0 = s * 32 + ((L >> 4) << 3);
      const float* W = (nn < C_OUT) ? (Wmu + nn) : (Wlv + (nn - C_OUT));
      unsigned short* dstp = bswz2 + (size_t)id2 * 8;
#pragma unroll
      for (int j = 0; j < 8; j++) dstp[j] = f2bf(W[(size_t)(k0 + j) * C_OUT]);
    } else if (idx < 6208) {     // zero row n of p1 (64 dwords)
      p1z[idx - 6144] = 0u;
    } else if (idx < 6272) {     // zero row n of p2
      p2z[idx - 6208] = 0u;
    }
    return;
  }
  __shared__ int h[NBUCK], c[NBUCK];
  h[tid] = 0;                    // TB == NBUCK == 1024
  __syncthreads();
  int e0 = wg * cap;
  int e1 = e0 + cap; if (e1 > E) e1 = E;
  for (int e = e0 + tid; e < e1; e += 1024)
    atomicAdd(&h[dst[e] >> 7], 1);
  __syncthreads();
  int v = h[tid];
  for (int ofs = 1; ofs < NBUCK; ofs <<= 1) {
    int add = (tid >= ofs) ? h[tid - ofs] : 0;
    __syncthreads();
    h[tid] += add;
    __syncthreads();
  }
  int excl = h[tid] - v;         // exclusive prefix within this segment
  cnt_arr[(size_t)wg * NBUCK + tid] = v;
  off_arr[(size_t)wg * NBUCK + tid] = excl;
  c[tid] = excl;
  __syncthreads();
  for (int e = e0 + tid; e < e1; e += 1024) {
    int d = dst[e];
    int pos = e0 + atomicAdd(&c[d >> 7], 1);   // private region [e0, e1)
    binned[pos] = (unsigned)src[e] | ((unsigned)(d & 127) << 17);
  }
}

// ---------------- P2 merged: bucket CSR build  ||  layer-1 GEMM --------------
// Blocks [0,nbk): per-bucket deg/dinv/row_start/rdeg + csr fill.
// Blocks [nbk, nbk+gemm_bks): gemm1, p1 = bf16(x@W1)  (UNFOLDED - no dinv).
// Both depend only on k_seg_bin outputs -> free co-scheduling.
__global__ __launch_bounds__(256) void k_build2(
    const unsigned* __restrict__ binned, const int* __restrict__ cnt_arr,
    const int* __restrict__ off_arr, int cap,
    int* __restrict__ row_start, int* __restrict__ rdeg,
    float* __restrict__ dinv, int* __restrict__ csr, int n, int nbk,
    const float* __restrict__ x, const unsigned short* __restrict__ bswz1,
    unsigned short* __restrict__ p1) {
  __shared__ unsigned eb[EBCAP];
  __shared__ int sc[256];
  __shared__ int deg[128], ex[128], cur[128];
  int t = threadIdx.x;
  if ((int)blockIdx.x < nbk) {
    // ---------------- bucket CSR build ----------------
    int b = blockIdx.x;
    int cnt = cnt_arr[(size_t)t * NBUCK + b];  // run of segment t in bucket b
    int off = off_arr[(size_t)t * NBUCK + b];
    sc[t] = cnt;
    __syncthreads();
    for (int ofs = 1; ofs < 256; ofs <<= 1) {
      int add = (t >= ofs) ? sc[t - ofs] : 0;
      __syncthreads();
      sc[t] += add;
      __syncthreads();
    }
    int lbase = sc[t] - cnt;
    int tot = sc[255];
    const unsigned* srcp = binned + (size_t)t * cap + off;
    for (int j = 0; j < cnt; ++j) {
      int ppos = lbase + j;
      if (ppos < EBCAP) eb[ppos] = srcp[j];
    }
    if (t < 128) deg[t] = 0;
    __syncthreads();
    if (tot > EBCAP) tot = EBCAP;              // never expected (mean 2046)
    for (int e = t; e < tot; e += 256)
      atomicAdd(&deg[eb[e] >> 17], 1);
    __syncthreads();
    if (t < 128) ex[t] = deg[t];
    __syncthreads();
    for (int ofs = 1; ofs < 128; ofs <<= 1) {
      int add = (t < 128 && t >= ofs) ? ex[t - ofs] : 0;
      __syncthreads();
      if (t < 128) ex[t] += add;
      __syncthreads();
    }
    if (t < 128) {
      int excl = ex[t] - deg[t];
      cur[t] = excl;
      int node = b * 128 + t;
      if (node < n) {
        row_start[node] = b * CAPB + excl;
        rdeg[node] = deg[t];
        dinv[node] = rsqrtf((float)deg[t] + 1.0f);
      }
    }
    if (b == 0 && t == 0) dinv[n] = 0.f;       // pad-slot weight
    __syncthreads();
    for (int e = t; e < tot; e += 256) {
      unsigned v = eb[e];
      int d = (int)(v >> 17);
      int pos = atomicAdd(&cur[d], 1);
      csr[(size_t)b * CAPB + pos] = (int)(v & 0x1FFFF);
    }
    return;
  }
  // ---------------- layer-1 GEMM (unfolded epilogue) ----------------
  {
    int chunk = (int)blockIdx.x - nbk;
    int wave = t >> 6, lane = t & 63;
    int lrow = lane & 15, lq = lane >> 4;
    int m0 = chunk * 64 + wave * 16;
    int arow = m0 + lrow;
    bool rv = arow < n;
    const float* ap = x + (size_t)(rv ? arow : 0) * C_IN + lq * 8;

    auto loadA = [&](int s) -> bf16x8 {
      const float* af = ap + s * 32;
      float4 u0 = rv ? *(const float4*)(af) : float4{0, 0, 0, 0};
      float4 u1 = rv ? *(const float4*)(af + 4) : float4{0, 0, 0, 0};
      union { unsigned short us[8]; bf16x8 v; } tmp;
      tmp.us[0] = f2bf(u0.x); tmp.us[1] = f2bf(u0.y);
      tmp.us[2] = f2bf(u0.z); tmp.us[3] = f2bf(u0.w);
      tmp.us[4] = f2bf(u1.x); tmp.us[5] = f2bf(u1.y);
      tmp.us[6] = f2bf(u1.z); tmp.us[7] = f2bf(u1.w);
      return tmp.v;
    };

    f32x4 acc[8];
#pragma unroll
    for (int tt = 0; tt < 8; tt++) acc[tt] = (f32x4){0.f, 0.f, 0.f, 0.f};

    bf16x8 a_cur = loadA(0);
    bf16x8 b_cur[8];
#pragma unroll
    for (int tt = 0; tt < 8; tt++)
      b_cur[tt] = *(const bf16x8*)(bswz1 + lane * 8 + tt * 512);

#pragma unroll
    for (int s = 0; s < C_IN / 32; ++s) {
      bf16x8 a_nxt = a_cur;
      bf16x8 b_nxt[8];
      if (s + 1 < C_IN / 32) {
        a_nxt = loadA(s + 1);
        const unsigned short* bp = bswz1 + (size_t)(s + 1) * 4096 + lane * 8;
#pragma unroll
        for (int tt = 0; tt < 8; tt++) b_nxt[tt] = *(const bf16x8*)(bp + tt * 512);
      }
#pragma unroll
      for (int tt = 0; tt < 8; tt++)
        acc[tt] = __builtin_amdgcn_mfma_f32_16x16x32_bf16(a_cur, b_cur[tt], acc[tt], 0, 0, 0);
      a_cur = a_nxt;
      if (s + 1 < C_IN / 32) {
#pragma unroll
        for (int tt = 0; tt < 8; tt++) b_cur[tt] = b_nxt[tt];
      }
    }
#pragma unroll
    for (int i = 0; i < 4; i++) {
      int rr = m0 + lq * 4 + i;
      if (rr < n) {
        unsigned short* cp = p1 + (size_t)rr * 128 + lrow;
#pragma unroll
        for (int tt = 0; tt < 8; tt++) cp[tt * 16] = f2bf(acc[tt][i]);
      }
    }
  }
}

// ---------------- weighted gather body (for unfolded p1) ---------------------
// Per 16-edge window: 16 bpermutes of src row + 16 bpermutes of dinv[src] +
// 16 uint4 loads + 128 FMAs. wl = dinv[sl] covers real/self/pad uniformly
// (dinv[n] = 0). Same VALU count as the unweighted body (FMA vs ADD).
#define AGG_V4_W_BODY                                                               \
  int tid = threadIdx.x;                                                            \
  int wid4 = blockIdx.x * 4 + (tid >> 6); /* 4 waves/WG */                          \
  int lane = tid & 63;                                                              \
  int li = lane & 15;                                                               \
  int node = (wid4 << 2) + (lane >> 4);                                             \
  int rs = 0, re = -1;                                                              \
  if (node < n) { rs = row_start[node]; re = rs + rdeg[node]; }                     \
  int mc = re - rs + 1; /* edges incl. self */                                      \
  mc = max(mc, __shfl_xor(mc, 16, 64));                                             \
  mc = max(mc, __shfl_xor(mc, 32, 64));                                             \
  int maxcnt = __builtin_amdgcn_readfirstlane(mc);                                  \
  const char* pb = (const char*)p;                                                  \
  unsigned loff = (unsigned)(li << 4);                                              \
  int vb = (lane & 48) << 2;                                                        \
  float acc0 = 0.f, acc1 = 0.f, acc2 = 0.f, acc3 = 0.f;                             \
  float acc4 = 0.f, acc5 = 0.f, acc6 = 0.f, acc7 = 0.f;                             \
  for (int t0 = 0; t0 < maxcnt; t0 += 16) {                                         \
    int s = rs + t0 + li;                                                           \
    int sl = n; /* zero row, weight 0 */                                            \
    if (s < re) sl = csr[s];                                                        \
    else if (s == re) sl = node; /* self edge */                                    \
    int wb = __float_as_int(dinv[sl]);                                              \
    unsigned o[16];                                                                 \
    _Pragma("unroll")                                                               \
    for (int k = 0; k < 16; ++k)                                                    \
      o[k] = ((unsigned)__builtin_amdgcn_ds_bpermute(vb + (k << 2), sl)) << 8;      \
    float wk[16];                                                                   \
    _Pragma("unroll")                                                               \
    for (int k = 0; k < 16; ++k)                                                    \
      wk[k] = __int_as_float(__builtin_amdgcn_ds_bpermute(vb + (k << 2), wb));      \
    uint4 v[16];                                                                    \
    _Pragma("unroll")                                                               \
    for (int k = 0; k < 16; ++k)                                                    \
      v[k] = *(const uint4*)(pb + (o[k] + loff));                                   \
    _Pragma("unroll")                                                               \
    for (int k = 0; k < 16; ++k) {                                                  \
      acc0 += bflo(v[k].x) * wk[k]; acc1 += bfhi(v[k].x) * wk[k];                   \
      acc2 += bflo(v[k].y) * wk[k]; acc3 += bfhi(v[k].y) * wk[k];                   \
      acc4 += bflo(v[k].z) * wk[k]; acc5 += bfhi(v[k].z) * wk[k];                   \
      acc6 += bflo(v[k].w) * wk[k]; acc7 += bfhi(v[k].w) * wk[k];                   \
    }                                                                               \
  }

// ---------------- unweighted gather body (for folded p2) ---------------------
#define AGG_V4_BODY                                                                 \
  int tid = threadIdx.x;                                                            \
  int wid4 = blockIdx.x * 4 + (tid >> 6); /* 4 waves/WG */                          \
  int lane = tid & 63;                                                              \
  int li = lane & 15;                                                               \
  int node = (wid4 << 2) + (lane >> 4);                                             \
  int rs = 0, re = -1;                                                              \
  if (node < n) { rs = row_start[node]; re = rs + rdeg[node]; }                     \
  int mc = re - rs + 1; /* edges incl. self */                                      \
  mc = max(mc, __shfl_xor(mc, 16, 64));                                             \
  mc = max(mc, __shfl_xor(mc, 32, 64));                                             \
  int maxcnt = __builtin_amdgcn_readfirstlane(mc);                                  \
  const char* pb = (const char*)p;                                                  \
  unsigned loff = (unsigned)(li << 4);                                              \
  int vb = (lane & 48) << 2;                                                        \
  float acc0 = 0.f, acc1 = 0.f, acc2 = 0.f, acc3 = 0.f;                             \
  float acc4 = 0.f, acc5 = 0.f, acc6 = 0.f, acc7 = 0.f;                             \
  for (int t0 = 0; t0 < maxcnt; t0 += 16) {                                         \
    int s = rs + t0 + li;                                                           \
    int sl = n; /* zero row */                                                      \
    if (s < re) sl = csr[s];                                                        \
    else if (s == re) sl = node; /* self edge */                                    \
    unsigned o[16];                                                                 \
    _Pragma("unroll")                                                               \
    for (int k = 0; k < 16; ++k)                                                    \
      o[k] = ((unsigned)__builtin_amdgcn_ds_bpermute(vb + (k << 2), sl)) << 8;      \
    uint4 v[16];                                                                    \
    _Pragma("unroll")                                                               \
    for (int k = 0; k < 16; ++k)                                                    \
      v[k] = *(const uint4*)(pb + (o[k] + loff));                                   \
    _Pragma("unroll")                                                               \
    for (int k = 0; k < 16; ++k) {                                                  \
      acc0 += bflo(v[k].x); acc1 += bfhi(v[k].x);                                   \
      acc2 += bflo(v[k].y); acc3 += bfhi(v[k].y);                                   \
      acc4 += bflo(v[k].z); acc5 += bfhi(v[k].z);                                   \
      acc6 += bflo(v[k].w); acc7 += bfhi(v[k].w);                                   \
    }                                                                               \
  }

// ---------------- FUSED: weighted agg+relu (layer1) -> A-tile -> GEMM2 -------
__global__ __launch_bounds__(256) void k_agg_gemm2(
    const unsigned short* __restrict__ p, const float* __restrict__ dinv,
    const int* __restrict__ row_start, const int* __restrict__ rdeg,
    const int* __restrict__ csr,
    const float* __restrict__ bias, const unsigned short* __restrict__ bswz2,
    unsigned short* __restrict__ p2, int n) {
  __shared__ unsigned short hs[16][136];
  AGG_V4_W_BODY
  int rwg = ((tid >> 6) << 2) + (lane >> 4);   // local row 0..15
  {
    uint4 u = {0u, 0u, 0u, 0u};
    if (node < n) {
      float di = dinv[node];
      float4 ba = *(const float4*)(bias + (li << 3));
      float4 bb = *(const float4*)(bias + (li << 3) + 4);
      float r0 = fmaxf(acc0 * di + ba.x, 0.f);
      float r1 = fmaxf(acc1 * di + ba.y, 0.f);
      float r2 = fmaxf(acc2 * di + ba.z, 0.f);
      float r3 = fmaxf(acc3 * di + ba.w, 0.f);
      float r4 = fmaxf(acc4 * di + bb.x, 0.f);
      float r5 = fmaxf(acc5 * di + bb.y, 0.f);
      float r6 = fmaxf(acc6 * di + bb.z, 0.f);
      float r7 = fmaxf(acc7 * di + bb.w, 0.f);
      u.x = (unsigned)f2bf(r0) | ((unsigned)f2bf(r1) << 16);
      u.y = (unsigned)f2bf(r2) | ((unsigned)f2bf(r3) << 16);
      u.z = (unsigned)f2bf(r4) | ((unsigned)f2bf(r5) << 16);
      u.w = (unsigned)f2bf(r6) | ((unsigned)f2bf(r7) << 16);
    }
    *(uint4*)(&hs[rwg][li << 3]) = u;          // 16B store, conflict-free
  }
  __syncthreads();

  // Phase B: GEMM2 over the WG's 16-row tile. wave w -> column tiles 2w, 2w+1
  int w = tid >> 6;
  int lrow = lane & 15, lq = lane >> 4;
  f32x4 g0 = (f32x4){0.f, 0.f, 0.f, 0.f};
  f32x4 g1 = (f32x4){0.f, 0.f, 0.f, 0.f};
#pragma unroll
  for (int s = 0; s < 4; ++s) {
    bf16x8 af = *(const bf16x8*)(&hs[lrow][(lq << 3) + s * 32]);
    const unsigned short* bp = bswz2 + s * 4096 + (w * 2) * 512 + lane * 8;
    bf16x8 bf0 = *(const bf16x8*)(bp);
    bf16x8 bf1 = *(const bf16x8*)(bp + 512);
    g0 = __builtin_amdgcn_mfma_f32_16x16x32_bf16(af, bf0, g0, 0, 0, 0);
    g1 = __builtin_amdgcn_mfma_f32_16x16x32_bf16(af, bf1, g1, 0, 0, 0);
  }
#pragma unroll
  for (int i = 0; i < 4; ++i) {
    int rr = blockIdx.x * 16 + (lq << 2) + i;
    if (rr < n) {
      float dsc = dinv[rr];                    // p2 stays FOLDED
      unsigned short* cp = p2 + (size_t)rr * 128 + lrow;
      cp[(w * 2) * 16]     = f2bf(g0[i] * dsc);
      cp[(w * 2 + 1) * 16] = f2bf(g1[i] * dsc);
    }
  }
}

// ---------------- output aggregation (layer 2+3, folded p2) ------------------
__global__ __launch_bounds__(256) void k_agg_out_bf(
    const unsigned short* __restrict__ p, const float* __restrict__ dinv,
    const int* __restrict__ row_start, const int* __restrict__ rdeg,
    const int* __restrict__ csr,
    const float* __restrict__ bmu, const float* __restrict__ blv,
    float* __restrict__ out, int n) {
  AGG_V4_BODY
  if (node < n) {
    float di = dinv[node];
    const float* bp = (li < 8) ? (bmu + (li << 3)) : (blv + ((li - 8) << 3));
    float* op = (li < 8) ? (out + (size_t)node * C_OUT + (li << 3))
                         : (out + (size_t)(n + node) * C_OUT + ((li - 8) << 3));
    float4 b0 = *(const float4*)(bp);
    float4 b1 = *(const float4*)(bp + 4);
    float4 o0 = {acc0 * di + b0.x, acc1 * di + b0.y,
                 acc2 * di + b0.z, acc3 * di + b0.w};
    float4 o1 = {acc4 * di + b1.x, acc5 * di + b1.y,
                 acc6 * di + b1.z, acc7 * di + b1.w};
    *(float4*)op = o0;
    *(float4*)(op + 4) = o1;
  }
}

// ---------------------------------------------------------------------------
extern "C" void kernel_launch(void* const* d_in, const int* in_sizes, int n_in,
                              void* d_out, int out_size, void* d_ws, size_t ws_size,
                              hipStream_t stream) {
  const float* x   = (const float*)d_in[0];
  const int*   ei  = (const int*)d_in[1];   // int32 on the wire (JAX x64 off)
  const float* W1  = (const float*)d_in[2];
  const float* b1  = (const float*)d_in[3];
  const float* Wmu = (const float*)d_in[4];
  const float* bmu = (const float*)d_in[5];
  const float* Wlv = (const float*)d_in[6];
  const float* blv = (const float*)d_in[7];
  float* out = (float*)d_out;

  const int n = in_sizes[0] / C_IN;
  const int E = in_sizes[1] / 2;
  const int* src = ei;
  const int* dst = ei + E;

  char* w = (char*)d_ws;
  auto alloc = [&](size_t bytes) -> void* {
    void* pp = (void*)w;
    w += (bytes + 255) & ~(size_t)255;
    return pp;
  };
  float*          dinv       = (float*)alloc((size_t)(n + 1) * 4);
  int*            row_start  = (int*)alloc((size_t)n * 4);
  int*            rdeg       = (int*)alloc((size_t)n * 4);
  int*            cnt_arr    = (int*)alloc((size_t)NSEG * NBUCK * 4);
  int*            off_arr    = (int*)alloc((size_t)NSEG * NBUCK * 4);
  unsigned*       binned     = (unsigned*)alloc((size_t)E * 4);
  int*            csr        = (int*)alloc((size_t)NBUCK * CAPB * 4);
  unsigned short* bswz1      = (unsigned short*)alloc((size_t)C_IN * 128 * 2);
  unsigned short* bswz2      = (unsigned short*)alloc((size_t)HID * 128 * 2);
  unsigned short* p1         = (unsigned short*)alloc((size_t)(n + 1) * 128 * 2);
  unsigned short* p2         = (unsigned short*)alloc((size_t)(n + 1) * 128 * 2);
  (void)ws_size; (void)n_in; (void)out_size;

  const int TB = 256;
  const int cap = (E + NSEG - 1) / NSEG;       // edges per segment
  const int gemm_bks = (n + 63) / 64;
  const int agg_bks = (n + 15) / 16;           // 4 nodes/wave, 4 waves/WG
  const int nbk = (n + 127) / 128;             // buckets containing nodes

  // ---- build stage 1: segment binning + weight prep ----
  k_seg_bin<<<NSEG + 7, 1024, 0, stream>>>(src, dst, E, cap, cnt_arr, off_arr,
                                           binned, W1, Wmu, Wlv, bswz1, bswz2,
                                           (unsigned*)(p1 + (size_t)n * 128),
                                           (unsigned*)(p2 + (size_t)n * 128));

  // ---- build stage 2: bucket CSR  ||  layer-1 GEMM (one dispatch) ----
  k_build2<<<nbk + gemm_bks, TB, 0, stream>>>(binned, cnt_arr, off_arr, cap,
                                              row_start, rdeg, dinv, csr, n, nbk,
                                              x, bswz1, p1);

  // ---- layer 1 agg (weighted) + relu fused with layer 2+3 GEMM ----
  k_agg_gemm2<<<agg_bks, TB, 0, stream>>>(p1, dinv, row_start, rdeg, csr, b1,
                                          bswz2, p2, n);

  // ---- layer 2+3 output aggregation ----
  k_agg_out_bf<<<agg_bks, TB, 0, stream>>>(p2, dinv, row_start, rdeg, csr,
                                           bmu, blv, out, n);
}